// Round 1
// baseline (2060.124 us; speedup 1.0000x reference)
//
#include <hip/hip_runtime.h>

#define N_ATOMS 50000
#define N_PAIRS 800000
#define N_EMB   128
#define N_DIST  100
#define N_HID   128
#define PPB     4   // pairs per block

// ---------------- kernel 1: afh = atom_features @ W_cf + b_cf ----------------
__global__ __launch_bounds__(128) void afh_kernel(
    const float* __restrict__ af, const float* __restrict__ Wcf,
    const float* __restrict__ bcf, float* __restrict__ afh) {
  const int a = blockIdx.x;
  const int t = threadIdx.x;
  const float* __restrict__ row = af + (size_t)a * N_EMB;  // uniform -> s_load
  float acc = bcf[t];
  #pragma unroll 4
  for (int k = 0; k < N_EMB; ++k)
    acc += row[k] * Wcf[k * N_HID + t];
  afh[(size_t)a * N_HID + t] = acc;
}

// -------- kernel 2: fused per-pair dh -> h -> tanh(h@Wfc) -> atomic agg ------
__global__ __launch_bounds__(128) void pair_kernel(
    const float* __restrict__ dist, const int* __restrict__ mi,
    const int* __restrict__ mj, const float* __restrict__ Wdf,
    const float* __restrict__ Wfc, const float* __restrict__ bdf,
    const float* __restrict__ afh, float* __restrict__ agg) {
  __shared__ float h_lds[PPB][N_HID];
  const int t = threadIdx.x;
  const long pbase = (long)blockIdx.x * PPB;

  // phase A: dh[pp][t] = b_df[t] + sum_k dist[p][k] * W_df[k][t]
  float acc[PPB];
  const float bd = bdf[t];
  #pragma unroll
  for (int pp = 0; pp < PPB; ++pp) acc[pp] = bd;

  const float* __restrict__ drow = dist + (size_t)pbase * N_DIST;
  #pragma unroll 2
  for (int k = 0; k < N_DIST; ++k) {
    const float w = Wdf[k * N_HID + t];        // vector, coalesced, L2-hot
    #pragma unroll
    for (int pp = 0; pp < PPB; ++pp)
      acc[pp] += drow[pp * N_DIST + k] * w;    // uniform -> s_load
  }

  // phase B: h = dh * afh[j], stage to LDS for the transpose
  #pragma unroll
  for (int pp = 0; pp < PPB; ++pp) {
    const int j = mj[pbase + pp];              // uniform -> s_load
    h_lds[pp][t] = acc[pp] * afh[(size_t)j * N_HID + t];
  }
  __syncthreads();

  // phase C: m[pp][t] = sum_k h[pp][k] * W_fc[k][t]
  float m[PPB];
  #pragma unroll
  for (int pp = 0; pp < PPB; ++pp) m[pp] = 0.f;

  for (int k4 = 0; k4 < N_HID / 4; ++k4) {
    float w[4];
    #pragma unroll
    for (int q = 0; q < 4; ++q)
      w[q] = Wfc[(k4 * 4 + q) * N_EMB + t];    // vector, coalesced, L2-hot
    #pragma unroll
    for (int pp = 0; pp < PPB; ++pp) {
      const float4 hv = ((const float4*)&h_lds[pp][0])[k4];  // ds_read_b128 broadcast
      m[pp] += hv.x * w[0] + hv.y * w[1] + hv.z * w[2] + hv.w * w[3];
    }
  }

  #pragma unroll
  for (int pp = 0; pp < PPB; ++pp) {
    const int i = mi[pbase + pp];              // uniform -> s_load
    atomicAdd(&agg[(size_t)i * N_EMB + t], tanhf(m[pp]));
  }
}

// --- kernel 3: out = agg - tanh((b_df*afh) @ W_fc) + atom_features -----------
__global__ __launch_bounds__(128) void out_kernel(
    const float* __restrict__ af, const float* __restrict__ afh,
    const float* __restrict__ Wfc, const float* __restrict__ bdf,
    const float* __restrict__ agg, float* __restrict__ out) {
  const int a = blockIdx.x;
  const int t = threadIdx.x;
  const float* __restrict__ hrow = afh + (size_t)a * N_HID;  // uniform -> s_load
  float acc = 0.f;
  #pragma unroll 4
  for (int k = 0; k < N_HID; ++k)
    acc += (bdf[k] * hrow[k]) * Wfc[k * N_EMB + t];
  const size_t idx = (size_t)a * N_EMB + t;
  out[idx] = agg[idx] - tanhf(acc) + af[idx];
}

extern "C" void kernel_launch(void* const* d_in, const int* in_sizes, int n_in,
                              void* d_out, int out_size, void* d_ws, size_t ws_size,
                              hipStream_t stream) {
  const float* af   = (const float*)d_in[0];
  const float* dist = (const float*)d_in[1];
  // d_in[2] atom_membership: unused by the reference computation
  const int*   mi   = (const int*)d_in[3];
  const int*   mj   = (const int*)d_in[4];
  const float* Wcf  = (const float*)d_in[5];
  const float* Wdf  = (const float*)d_in[6];
  const float* Wfc  = (const float*)d_in[7];
  const float* bcf  = (const float*)d_in[8];
  const float* bdf  = (const float*)d_in[9];
  float* out = (float*)d_out;

  float* afh = (float*)d_ws;                              // 50000*128 f32 = 25.6 MB
  float* agg = afh + (size_t)N_ATOMS * N_HID;             // 50000*128 f32 = 25.6 MB

  hipMemsetAsync(agg, 0, (size_t)N_ATOMS * N_EMB * sizeof(float), stream);
  afh_kernel<<<N_ATOMS, 128, 0, stream>>>(af, Wcf, bcf, afh);
  pair_kernel<<<N_PAIRS / PPB, 128, 0, stream>>>(dist, mi, mj, Wdf, Wfc, bdf, afh, agg);
  out_kernel<<<N_ATOMS, 128, 0, stream>>>(af, afh, Wfc, bdf, agg, out);
}

// Round 2
// 882.333 us; speedup vs baseline: 2.3349x; 2.3349x over previous
//
#include <hip/hip_runtime.h>
#include <hip/hip_bf16.h>

#define N_ATOMS 50000
#define N_PAIRS 800000
#define N_EMB   128
#define N_DIST  100
#define N_HID   128
#define TP      128   // pairs per block (8 waves x 16 rows)

typedef __attribute__((ext_vector_type(8))) short bf16x8;
typedef __attribute__((ext_vector_type(4))) float f32x4;

__device__ __forceinline__ short f2b(float x) {
  union { float f; unsigned u; } v; v.f = x;
  unsigned r = (v.u + 0x7FFF + ((v.u >> 16) & 1)) >> 16;   // RNE
  return (short)r;
}
__device__ __forceinline__ float b2f(short b) {
  union { unsigned u; float f; } v; v.u = ((unsigned)(unsigned short)b) << 16;
  return v.f;
}

// fragment-order index for B operand of mfma_f32_16x16x32_bf16:
// [kstep][ntile][lane=quad*16+n15][j], element (k,n): quad=(k>>3)&3, j=k&7
__device__ __forceinline__ int frag_idx(int k, int n) {
  return ((((k >> 5) * 8 + (n >> 4)) * 64) + (((k >> 3) & 3) * 16) + (n & 15)) * 8 + (k & 7);
}

// ---------------- kernel 1: afh = atom_features @ W_cf + b_cf ----------------
__global__ __launch_bounds__(128) void afh_kernel(
    const float* __restrict__ af, const float* __restrict__ Wcf,
    const float* __restrict__ bcf, float* __restrict__ afh) {
  const int t = threadIdx.x;
  const long a0 = (long)blockIdx.x * 8;
  float acc[8];
  const float bc = bcf[t];
  #pragma unroll
  for (int aa = 0; aa < 8; ++aa) acc[aa] = bc;
  #pragma unroll 4
  for (int k = 0; k < N_EMB; ++k) {
    const float wv = Wcf[k * N_HID + t];          // vector, coalesced, L2-hot
    #pragma unroll
    for (int aa = 0; aa < 8; ++aa)
      acc[aa] += af[(a0 + aa) * N_EMB + k] * wv;  // uniform -> s_load
  }
  #pragma unroll
  for (int aa = 0; aa < 8; ++aa)
    afh[(a0 + aa) * N_HID + t] = acc[aa];
}

// -------- kernel 2: fused MFMA per-pair dh -> h -> tanh(h@Wfc) -> seg-agg ----
__global__ __launch_bounds__(512, 4) void pair_kernel(
    const float* __restrict__ dist, const int* __restrict__ mi,
    const int* __restrict__ mj, const float* __restrict__ Wdf,
    const float* __restrict__ Wfc, const float* __restrict__ bdf,
    const float* __restrict__ afh, float* __restrict__ agg) {
  __shared__ short WS[128 * 128];   // 32KB: weight in B-fragment order (Wdf then Wfc)
  __shared__ short HS[TP * 128];    // 32KB: h (bf16), then msg (bf16); xor-swizzled

  const int tid = threadIdx.x;
  const int lane = tid & 63;
  const int w = tid >> 6;           // wave 0..7 -> rows [16w,16w+16)
  const int lane15 = lane & 15;
  const int quad = lane >> 4;
  const long pbase = (long)blockIdx.x * TP;
  const int R = w * 16;

  // ---- stage Wdf into fragment order (zero-pad k>=100) ----
  for (int e = tid; e < 128 * 128; e += 512) {
    const int k = e >> 7, n = e & 127;
    const float v = (k < N_DIST) ? Wdf[k * N_HID + n] : 0.f;
    WS[frag_idx(k, n)] = f2b(v);
  }
  __syncthreads();

  // ---- phase A: dh[16x128] = dist_tile @ Wdf + bdf ----
  f32x4 acc[8];
  #pragma unroll
  for (int nt = 0; nt < 8; ++nt) {
    const float b = bdf[nt * 16 + lane15];
    acc[nt] = (f32x4){b, b, b, b};
  }
  const float* __restrict__ drow = dist + (pbase + R + lane15) * (long)N_DIST;
  for (int ks = 0; ks < 4; ++ks) {
    bf16x8 a;
    const int k0 = ks * 32 + quad * 8;
    if (ks < 3) {                                   // k0+7 <= 95 < 100, aligned 16B
      const float4 x = *(const float4*)(drow + k0);
      const float4 y = *(const float4*)(drow + k0 + 4);
      a[0] = f2b(x.x); a[1] = f2b(x.y); a[2] = f2b(x.z); a[3] = f2b(x.w);
      a[4] = f2b(y.x); a[5] = f2b(y.y); a[6] = f2b(y.z); a[7] = f2b(y.w);
    } else {                                        // tail: k 96..99 valid (quad 0)
      #pragma unroll
      for (int j = 0; j < 8; ++j)
        a[j] = (k0 + j < N_DIST) ? f2b(drow[k0 + j]) : (short)0;
    }
    #pragma unroll
    for (int nt = 0; nt < 8; ++nt) {
      const bf16x8 b = *(const bf16x8*)&WS[((ks * 8 + nt) * 64 + lane) * 8];
      acc[nt] = __builtin_amdgcn_mfma_f32_16x16x32_bf16(a, b, acc[nt], 0, 0, 0);
    }
  }
  __syncthreads();                                  // all waves done reading Wdf

  // ---- restage Wfc into WS ----
  for (int e = tid; e < 128 * 128; e += 512) {
    const int k = e >> 7, n = e & 127;
    WS[frag_idx(k, n)] = f2b(Wfc[k * N_EMB + n]);
  }

  // ---- phase B: h = dh * afh[mj[p]], bf16 -> HS (own rows; swizzled) ----
  #pragma unroll
  for (int reg = 0; reg < 4; ++reg) {
    const int r = R + quad * 4 + reg;               // C-layout row
    const long j = mj[pbase + r];                   // uniform per 16 lanes
    const float* __restrict__ arow = afh + j * N_HID;
    #pragma unroll
    for (int nt = 0; nt < 8; ++nt) {
      const int col = nt * 16 + lane15;
      const float h = acc[nt][reg] * arow[col];     // 64B-coalesced gather
      const int ch = (col >> 3) ^ (r & 15);
      HS[(r << 7) + (ch << 3) + (col & 7)] = f2b(h);
    }
  }
  __syncthreads();                                  // Wfc staged, HS visible

  // ---- phase C: msg[16x128] = h @ Wfc ----
  f32x4 acc2[8];
  #pragma unroll
  for (int nt = 0; nt < 8; ++nt) acc2[nt] = (f32x4){0.f, 0.f, 0.f, 0.f};
  const int m = R + lane15;                         // A-layout row
  for (int ks = 0; ks < 4; ++ks) {
    const int ch = (ks * 4 + quad) ^ lane15;        // (m & 15) == lane15
    const bf16x8 a = *(const bf16x8*)&HS[(m << 7) + (ch << 3)];  // 2-way max, free
    #pragma unroll
    for (int nt = 0; nt < 8; ++nt) {
      const bf16x8 b = *(const bf16x8*)&WS[((ks * 8 + nt) * 64 + lane) * 8];
      acc2[nt] = __builtin_amdgcn_mfma_f32_16x16x32_bf16(a, b, acc2[nt], 0, 0, 0);
    }
  }

  // ---- epilogue: tanh -> HS as msg (own rows only; no barrier needed) ----
  #pragma unroll
  for (int reg = 0; reg < 4; ++reg) {
    const int r = R + quad * 4 + reg;
    #pragma unroll
    for (int nt = 0; nt < 8; ++nt) {
      const int col = nt * 16 + lane15;
      const float tv = tanhf(acc2[nt][reg]);
      const int ch = (col >> 3) ^ (r & 15);
      HS[(r << 7) + (ch << 3) + (col & 7)] = f2b(tv);
    }
  }
  __syncthreads();

  // ---- segmented reduction over sorted mi: one atomic per boundary ----
  {
    const int col = tid & 127;
    const int seg = tid >> 7;                       // 0..3, wave-uniform
    const int r0 = seg * 32;
    float s = 0.f;
    int cur = mi[pbase + r0];                       // uniform -> s_load
    for (int rr = 0; rr < 32; ++rr) {
      const int r = r0 + rr;
      const int idx = mi[pbase + r];                // uniform -> s_load
      if (idx != cur) {                             // wave-uniform branch
        atomicAdd(&agg[(size_t)cur * N_EMB + col], s);
        s = 0.f; cur = idx;
      }
      const int ch = (col >> 3) ^ (r & 15);
      s += b2f(HS[(r << 7) + (ch << 3) + (col & 7)]);
    }
    atomicAdd(&agg[(size_t)cur * N_EMB + col], s);
  }
}

// --- kernel 3: out = agg - tanh((b_df*afh) @ W_fc) + atom_features -----------
__global__ __launch_bounds__(128) void out_kernel(
    const float* __restrict__ af, const float* __restrict__ afh,
    const float* __restrict__ Wfc, const float* __restrict__ bdf,
    const float* __restrict__ agg, float* __restrict__ out) {
  const int t = threadIdx.x;
  const long a0 = (long)blockIdx.x * 8;
  float acc[8];
  #pragma unroll
  for (int aa = 0; aa < 8; ++aa) acc[aa] = 0.f;
  #pragma unroll 4
  for (int k = 0; k < N_HID; ++k) {
    const float wv = Wfc[k * N_EMB + t];            // vector, coalesced, L2-hot
    const float bk = bdf[k];                        // uniform -> s_load
    #pragma unroll
    for (int aa = 0; aa < 8; ++aa)
      acc[aa] += bk * afh[(a0 + aa) * N_HID + k] * wv;
  }
  #pragma unroll
  for (int aa = 0; aa < 8; ++aa) {
    const size_t idx = (size_t)(a0 + aa) * N_EMB + t;
    out[idx] = agg[idx] - tanhf(acc[aa]) + af[idx];
  }
}

extern "C" void kernel_launch(void* const* d_in, const int* in_sizes, int n_in,
                              void* d_out, int out_size, void* d_ws, size_t ws_size,
                              hipStream_t stream) {
  const float* af   = (const float*)d_in[0];
  const float* dist = (const float*)d_in[1];
  const int*   mi   = (const int*)d_in[3];
  const int*   mj   = (const int*)d_in[4];
  const float* Wcf  = (const float*)d_in[5];
  const float* Wdf  = (const float*)d_in[6];
  const float* Wfc  = (const float*)d_in[7];
  const float* bcf  = (const float*)d_in[8];
  const float* bdf  = (const float*)d_in[9];
  float* out = (float*)d_out;

  float* afh = (float*)d_ws;                        // 25.6 MB
  float* agg = afh + (size_t)N_ATOMS * N_HID;       // 25.6 MB

  hipMemsetAsync(agg, 0, (size_t)N_ATOMS * N_EMB * sizeof(float), stream);
  afh_kernel<<<N_ATOMS / 8, 128, 0, stream>>>(af, Wcf, bcf, afh);
  pair_kernel<<<N_PAIRS / TP, 512, 0, stream>>>(dist, mi, mj, Wdf, Wfc, bdf, afh, agg);
  out_kernel<<<N_ATOMS / 8, 128, 0, stream>>>(af, afh, Wfc, bdf, agg, out);
}

// Round 3
// 621.007 us; speedup vs baseline: 3.3174x; 1.4208x over previous
//
#include <hip/hip_runtime.h>
#include <hip/hip_bf16.h>

#define N_ATOMS 50000
#define N_PAIRS 800000
#define N_EMB   128
#define N_DIST  100
#define N_HID   128
#define TP      128   // pairs per block (8 waves x 16 rows)

typedef __attribute__((ext_vector_type(8))) short bf16x8;
typedef __attribute__((ext_vector_type(4))) float f32x4;

__device__ __forceinline__ short f2b(float x) {
  union { float f; unsigned u; } v; v.f = x;
  unsigned r = (v.u + 0x7FFF + ((v.u >> 16) & 1)) >> 16;   // RNE
  return (short)r;
}
__device__ __forceinline__ float b2f(short b) {
  union { unsigned u; float f; } v; v.u = ((unsigned)(unsigned short)b) << 16;
  return v.f;
}
__device__ __forceinline__ float fast_tanh(float x) {
  // tanh(x) = 1 - 2/(exp2(x*2*log2e)+1); exact at +-inf, ~1e-6 abs error
  const float z = __builtin_amdgcn_exp2f(x * 2.8853900817779268f);
  return 1.f - 2.f * __builtin_amdgcn_rcpf(z + 1.f);
}

// fragment-order index for B operand of mfma_f32_16x16x32_bf16:
// [kstep][ntile][lane=quad*16+n15][j], element (k,n): quad=(k>>3)&3, j=k&7
__device__ __forceinline__ int frag_idx(int k, int n) {
  return ((((k >> 5) * 8 + (n >> 4)) * 64) + (((k >> 3) & 3) * 16) + (n & 15)) * 8 + (k & 7);
}

// async 16B global -> LDS (wave-uniform base + lane*16 pattern)
__device__ __forceinline__ void g2lds16(const void* g, void* l) {
  __builtin_amdgcn_global_load_lds(
      (const __attribute__((address_space(1))) unsigned*)g,
      (__attribute__((address_space(3))) unsigned*)l, 16, 0, 0);
}
// stage 32KB of pre-formatted weights (16384 shorts) with 512 threads
__device__ __forceinline__ void stage_weights(const short* __restrict__ src,
                                              short* WS, int tid) {
  #pragma unroll
  for (int r = 0; r < 4; ++r) {
    const int off = (r * 512 + tid) * 8;   // 8 shorts = 16B per issue
    g2lds16(src + off, WS + off);
  }
}

// ------------- kernel 0: format weights to bf16 fragment order (once) -------
__global__ __launch_bounds__(256) void prep_kernel(
    const float* __restrict__ Wcf, const float* __restrict__ Wdf,
    const float* __restrict__ Wfc, short* __restrict__ Wcf_f,
    short* __restrict__ Wdf_f, short* __restrict__ Wfc_f) {
  const int e = blockIdx.x * 256 + threadIdx.x;   // 16384 total
  const int k = e >> 7, n = e & 127;
  const int fi = frag_idx(k, n);
  Wcf_f[fi] = f2b(Wcf[k * N_HID + n]);
  Wfc_f[fi] = f2b(Wfc[k * N_EMB + n]);
  Wdf_f[fi] = (k < N_DIST) ? f2b(Wdf[k * N_HID + n]) : (short)0;
}

// ---------------- kernel 1: afh = atom_features @ W_cf + b_cf (MFMA) --------
__global__ __launch_bounds__(512) void afh_kernel(
    const float* __restrict__ af, const short* __restrict__ Wcf_f,
    const float* __restrict__ bcf, float* __restrict__ afh) {
  __shared__ short WS[128 * 128];
  const int tid = threadIdx.x;
  const int lane = tid & 63, w = tid >> 6;
  const int lane15 = lane & 15, quad = lane >> 4;
  const int a0 = blockIdx.x * 128;

  stage_weights(Wcf_f, WS, tid);

  f32x4 acc[8];
  #pragma unroll
  for (int nt = 0; nt < 8; ++nt) {
    const float b = bcf[nt * 16 + lane15];
    acc[nt] = (f32x4){b, b, b, b};
  }
  const int arow = min(a0 + w * 16 + lane15, N_ATOMS - 1);
  const float* __restrict__ p = af + (long)arow * N_EMB;
  __syncthreads();                                  // WS staged

  for (int ks = 0; ks < 4; ++ks) {
    const int k0 = ks * 32 + quad * 8;
    const float4 x = *(const float4*)(p + k0);
    const float4 y = *(const float4*)(p + k0 + 4);
    bf16x8 a;
    a[0] = f2b(x.x); a[1] = f2b(x.y); a[2] = f2b(x.z); a[3] = f2b(x.w);
    a[4] = f2b(y.x); a[5] = f2b(y.y); a[6] = f2b(y.z); a[7] = f2b(y.w);
    #pragma unroll
    for (int nt = 0; nt < 8; ++nt) {
      const bf16x8 b = *(const bf16x8*)&WS[((ks * 8 + nt) * 64 + lane) * 8];
      acc[nt] = __builtin_amdgcn_mfma_f32_16x16x32_bf16(a, b, acc[nt], 0, 0, 0);
    }
  }
  #pragma unroll
  for (int reg = 0; reg < 4; ++reg) {
    const int row = a0 + w * 16 + quad * 4 + reg;
    if (row < N_ATOMS) {
      #pragma unroll
      for (int nt = 0; nt < 8; ++nt)
        afh[(long)row * N_HID + nt * 16 + lane15] = acc[nt][reg];
    }
  }
}

// -------- kernel 2: fused MFMA per-pair dh -> h -> tanh(h@Wfc) -> seg-agg ----
__global__ __launch_bounds__(512, 4) void pair_kernel(
    const float* __restrict__ dist, const int* __restrict__ mi,
    const int* __restrict__ mj, const short* __restrict__ Wdf_f,
    const short* __restrict__ Wfc_f, const float* __restrict__ bdf,
    const float* __restrict__ afh, float* __restrict__ agg) {
  __shared__ short WS[128 * 128];   // 32KB: weights (Wdf then Wfc), frag order
  __shared__ short HS[TP * 128];    // 32KB: h then msg (bf16), xor-swizzled

  const int tid = threadIdx.x;
  const int lane = tid & 63;
  const int w = tid >> 6;           // wave 0..7 -> rows [16w,16w+16)
  const int lane15 = lane & 15;
  const int quad = lane >> 4;
  const long pbase = (long)blockIdx.x * TP;
  const int R = w * 16;

  stage_weights(Wdf_f, WS, tid);    // async

  // ---- phase A: dh[16x128] = dist_tile @ Wdf + bdf ----
  f32x4 acc[8];
  #pragma unroll
  for (int nt = 0; nt < 8; ++nt) {
    const float b = bdf[nt * 16 + lane15];
    acc[nt] = (f32x4){b, b, b, b};
  }
  const float* __restrict__ drow = dist + (pbase + R + lane15) * (long)N_DIST;
  __syncthreads();                                  // WS = Wdf staged

  for (int ks = 0; ks < 4; ++ks) {
    bf16x8 a;
    const int k0 = ks * 32 + quad * 8;
    if (ks < 3) {                                   // k0+7 <= 95 < 100, aligned 16B
      const float4 x = *(const float4*)(drow + k0);
      const float4 y = *(const float4*)(drow + k0 + 4);
      a[0] = f2b(x.x); a[1] = f2b(x.y); a[2] = f2b(x.z); a[3] = f2b(x.w);
      a[4] = f2b(y.x); a[5] = f2b(y.y); a[6] = f2b(y.z); a[7] = f2b(y.w);
    } else {                                        // tail: k 96..99 valid (quad 0)
      #pragma unroll
      for (int j = 0; j < 8; ++j)
        a[j] = (k0 + j < N_DIST) ? f2b(drow[k0 + j]) : (short)0;
    }
    #pragma unroll
    for (int nt = 0; nt < 8; ++nt) {
      const bf16x8 b = *(const bf16x8*)&WS[((ks * 8 + nt) * 64 + lane) * 8];
      acc[nt] = __builtin_amdgcn_mfma_f32_16x16x32_bf16(a, b, acc[nt], 0, 0, 0);
    }
  }
  __syncthreads();                                  // all waves done reading Wdf

  stage_weights(Wfc_f, WS, tid);                    // async; overlaps phase B

  // ---- phase B: h = dh * afh[mj[p]], bf16 -> HS (own rows; swizzled) ----
  #pragma unroll
  for (int reg = 0; reg < 4; ++reg) {
    const int r = R + quad * 4 + reg;               // C-layout row
    const long j = mj[pbase + r];                   // uniform per 16 lanes
    const float* __restrict__ arow = afh + j * N_HID;
    #pragma unroll
    for (int nt = 0; nt < 8; ++nt) {
      const int col = nt * 16 + lane15;
      const float h = acc[nt][reg] * arow[col];     // 64B-coalesced gather
      const int ch = (col >> 3) ^ (r & 15);
      HS[(r << 7) + (ch << 3) + (col & 7)] = f2b(h);
    }
  }
  __syncthreads();                                  // Wfc staged, HS visible

  // ---- phase C: msg[16x128] = h @ Wfc ----
  f32x4 acc2[8];
  #pragma unroll
  for (int nt = 0; nt < 8; ++nt) acc2[nt] = (f32x4){0.f, 0.f, 0.f, 0.f};
  const int m = R + lane15;                         // A-layout row
  for (int ks = 0; ks < 4; ++ks) {
    const int ch = (ks * 4 + quad) ^ lane15;        // (m & 15) == lane15
    const bf16x8 a = *(const bf16x8*)&HS[(m << 7) + (ch << 3)];  // 2-way max, free
    #pragma unroll
    for (int nt = 0; nt < 8; ++nt) {
      const bf16x8 b = *(const bf16x8*)&WS[((ks * 8 + nt) * 64 + lane) * 8];
      acc2[nt] = __builtin_amdgcn_mfma_f32_16x16x32_bf16(a, b, acc2[nt], 0, 0, 0);
    }
  }

  // ---- epilogue: tanh -> HS as msg (own rows only; no barrier needed) ----
  #pragma unroll
  for (int reg = 0; reg < 4; ++reg) {
    const int r = R + quad * 4 + reg;
    #pragma unroll
    for (int nt = 0; nt < 8; ++nt) {
      const int col = nt * 16 + lane15;
      const float tv = fast_tanh(acc2[nt][reg]);
      const int ch = (col >> 3) ^ (r & 15);
      HS[(r << 7) + (ch << 3) + (col & 7)] = f2b(tv);
    }
  }
  __syncthreads();

  // ---- segmented reduction over sorted mi: one atomic per boundary ----
  {
    const int col = tid & 127;
    const int seg = tid >> 7;                       // 0..3, wave-uniform
    const int r0 = seg * 32;
    float s = 0.f;
    int cur = mi[pbase + r0];                       // uniform -> s_load
    for (int rr = 0; rr < 32; ++rr) {
      const int r = r0 + rr;
      const int idx = mi[pbase + r];                // uniform -> s_load
      if (idx != cur) {                             // wave-uniform branch
        atomicAdd(&agg[(size_t)cur * N_EMB + col], s);
        s = 0.f; cur = idx;
      }
      const int ch = (col >> 3) ^ (r & 15);
      s += b2f(HS[(r << 7) + (ch << 3) + (col & 7)]);
    }
    atomicAdd(&agg[(size_t)cur * N_EMB + col], s);
  }
}

// --- kernel 3: out = agg - tanh((b_df*afh) @ W_fc) + atom_features (MFMA) ---
__global__ __launch_bounds__(512) void out_kernel(
    const float* __restrict__ af, const float* __restrict__ afh,
    const short* __restrict__ Wfc_f, const float* __restrict__ bdf,
    const float* __restrict__ agg, float* __restrict__ out) {
  __shared__ short WS[128 * 128];
  const int tid = threadIdx.x;
  const int lane = tid & 63, w = tid >> 6;
  const int lane15 = lane & 15, quad = lane >> 4;
  const int a0 = blockIdx.x * 128;

  stage_weights(Wfc_f, WS, tid);

  f32x4 acc[8];
  #pragma unroll
  for (int nt = 0; nt < 8; ++nt) acc[nt] = (f32x4){0.f, 0.f, 0.f, 0.f};
  const int arow = min(a0 + w * 16 + lane15, N_ATOMS - 1);
  const float* __restrict__ p = afh + (long)arow * N_HID;
  __syncthreads();                                  // WS staged

  for (int ks = 0; ks < 4; ++ks) {
    const int k0 = ks * 32 + quad * 8;
    const float4 x = *(const float4*)(p + k0);
    const float4 y = *(const float4*)(p + k0 + 4);
    const float4 bx = *(const float4*)(bdf + k0);
    const float4 by = *(const float4*)(bdf + k0 + 4);
    bf16x8 a;
    a[0] = f2b(x.x * bx.x); a[1] = f2b(x.y * bx.y);
    a[2] = f2b(x.z * bx.z); a[3] = f2b(x.w * bx.w);
    a[4] = f2b(y.x * by.x); a[5] = f2b(y.y * by.y);
    a[6] = f2b(y.z * by.z); a[7] = f2b(y.w * by.w);
    #pragma unroll
    for (int nt = 0; nt < 8; ++nt) {
      const bf16x8 b = *(const bf16x8*)&WS[((ks * 8 + nt) * 64 + lane) * 8];
      acc[nt] = __builtin_amdgcn_mfma_f32_16x16x32_bf16(a, b, acc[nt], 0, 0, 0);
    }
  }
  #pragma unroll
  for (int reg = 0; reg < 4; ++reg) {
    const int row = a0 + w * 16 + quad * 4 + reg;
    if (row < N_ATOMS) {
      #pragma unroll
      for (int nt = 0; nt < 8; ++nt) {
        const size_t idx = (size_t)row * N_EMB + nt * 16 + lane15;
        out[idx] = agg[idx] - fast_tanh(acc[nt][reg]) + af[idx];
      }
    }
  }
}

extern "C" void kernel_launch(void* const* d_in, const int* in_sizes, int n_in,
                              void* d_out, int out_size, void* d_ws, size_t ws_size,
                              hipStream_t stream) {
  const float* af   = (const float*)d_in[0];
  const float* dist = (const float*)d_in[1];
  const int*   mi   = (const int*)d_in[3];
  const int*   mj   = (const int*)d_in[4];
  const float* Wcf  = (const float*)d_in[5];
  const float* Wdf  = (const float*)d_in[6];
  const float* Wfc  = (const float*)d_in[7];
  const float* bcf  = (const float*)d_in[8];
  const float* bdf  = (const float*)d_in[9];
  float* out = (float*)d_out;

  float* afh = (float*)d_ws;                        // 25.6 MB
  float* agg = afh + (size_t)N_ATOMS * N_HID;       // 25.6 MB
  short* Wcf_f = (short*)(agg + (size_t)N_ATOMS * N_EMB);  // 3 x 32KB, frag order
  short* Wdf_f = Wcf_f + 128 * 128;
  short* Wfc_f = Wdf_f + 128 * 128;

  hipMemsetAsync(agg, 0, (size_t)N_ATOMS * N_EMB * sizeof(float), stream);
  prep_kernel<<<64, 256, 0, stream>>>(Wcf, Wdf, Wfc, Wcf_f, Wdf_f, Wfc_f);
  afh_kernel<<<(N_ATOMS + 127) / 128, 512, 0, stream>>>(af, Wcf_f, bcf, afh);
  pair_kernel<<<N_PAIRS / TP, 512, 0, stream>>>(dist, mi, mj, Wdf_f, Wfc_f, bdf, afh, agg);
  out_kernel<<<(N_ATOMS + 127) / 128, 512, 0, stream>>>(af, afh, Wfc_f, bdf, agg, out);
}